// Round 4
// baseline (250.528 us; speedup 1.0000x reference)
//
#include <hip/hip_runtime.h>
#include <hip/hip_bf16.h>

#define SEQ 512
#define EMB 256
#define NHEAD 8
#define HD 32

using bf16x8 = __attribute__((ext_vector_type(8))) short;
using f32x4  = __attribute__((ext_vector_type(4))) float;

static __device__ __forceinline__ unsigned short f2bf(float x) {
    union { float f; unsigned int u; } v; v.f = x;
    unsigned int r = v.u + 0x7FFFu + ((v.u >> 16) & 1u);
    return (unsigned short)(r >> 16);
}
static __device__ __forceinline__ float bf2f(unsigned short v) {
    union { unsigned int u; float f; } w; w.u = ((unsigned int)v) << 16; return w.f;
}

// ---------------- prep: gather embeds, build masked-concat A (bf16) + query (bf16)
__global__ __launch_bounds__(256) void prep_kernel(
    const int* __restrict__ item_inputs,
    const int* __restrict__ label_inputs,
    const int* __restrict__ item_ids,
    const float* __restrict__ embeds,
    unsigned short* __restrict__ Abig,   // 16384 x 512 bf16
    unsigned short* __restrict__ qbf)    // 16384 x 256 bf16
{
    int t = threadIdx.x;
    int r = blockIdx.x * 2 + (t >> 7);
    int j = (t & 127) * 2;
    int item = item_inputs[r];
    int lab  = label_inputs[r];
    int qid  = item_ids[r];
    float2 e2 = *(const float2*)(embeds + (size_t)item * EMB + j);
    ushort2 on  = make_ushort2(f2bf(e2.x), f2bf(e2.y));
    ushort2 off = make_ushort2(0, 0);
    *(ushort2*)(Abig + (size_t)r * 512 + j)       = lab ? on : off;
    *(ushort2*)(Abig + (size_t)r * 512 + 256 + j) = lab ? off : on;
    float2 q2 = *(const float2*)(embeds + (size_t)qid * EMB + j);
    *(ushort2*)(qbf + (size_t)r * 256 + j) = make_ushort2(f2bf(q2.x), f2bf(q2.y));
}

// ---------------- merged weight prep + logits init
__global__ __launch_bounds__(256) void wcombo_kernel(
    const float* __restrict__ W_in,
    const float* __restrict__ Wq,
    const float* __restrict__ Wk,
    const float* __restrict__ Wv,
    const float* __restrict__ Wout,
    const float* __restrict__ bv,
    const float* __restrict__ bout,
    unsigned short* __restrict__ WTin,   // 256 x 512
    unsigned short* __restrict__ WTq,    // 256 x 256
    unsigned short* __restrict__ WTk,    // 256 x 256
    float* __restrict__ Wvw,             // 256 x 8
    float* __restrict__ bvw,             // 8
    float* __restrict__ logits)          // init to bout
{
    int idx = blockIdx.x * 256 + threadIdx.x;
    if (idx < 131072) {                       // WTin[n][k] = W_in[k][n], K=512
        int n = idx >> 9, k = idx & 511;
        WTin[idx] = f2bf(W_in[(size_t)k * 256 + n]);
    } else if (idx < 196608) {                // WTq, K=256
        int i = idx - 131072;
        int n = i >> 8, k = i & 255;
        WTq[i] = f2bf(Wq[(size_t)k * 256 + n]);
    } else if (idx < 262144) {                // WTk, K=256
        int i = idx - 196608;
        int n = i >> 8, k = i & 255;
        WTk[i] = f2bf(Wk[(size_t)k * 256 + n]);
    } else if (idx < 264192) {                // Wvw[c][h] = sum_d Wv[c][32h+d]*Wout[32h+d]
        int i = idx - 262144;
        int c = i >> 3, h = i & 7;
        float s = 0.f;
        #pragma unroll
        for (int d = 0; d < 32; d++) s += Wv[(size_t)c * 256 + h * 32 + d] * Wout[h * 32 + d];
        Wvw[i] = s;
    } else if (idx < 264200) {                // bvw[h]
        int h = idx - 264192;
        float s = 0.f;
        #pragma unroll
        for (int d = 0; d < 32; d++) s += bv[h * 32 + d] * Wout[h * 32 + d];
        bvw[h] = s;
    } else if (idx < 280584) {                // logits init = bout
        logits[idx - 264200] = bout[0];
    }
}

// ---------------- MFMA GEMM body: C(M x 256) = A(M x KDIM) * BT^T + bias
template<int KDIM, int RELU, int OUTBF>
static __device__ __forceinline__ void gemm_body(
    const unsigned short* __restrict__ A,
    const unsigned short* __restrict__ BT,
    const float* __restrict__ bias,
    void* __restrict__ Cout, float scale)
{
    __shared__ unsigned short As[64][40];
    __shared__ unsigned short Bs[128][40];
    const int t = threadIdx.x;
    const int row0 = blockIdx.x * 64;
    const int col0 = blockIdx.y * 128;
    const int wid = t >> 6, lane = t & 63;
    const int wm = wid & 1, wn = wid >> 1;
    const int lg = lane >> 4, l15 = lane & 15;

    f32x4 acc[2][4];
    #pragma unroll
    for (int i = 0; i < 2; i++)
        #pragma unroll
        for (int j = 0; j < 4; j++) acc[i][j] = (f32x4){0.f, 0.f, 0.f, 0.f};

    const int arow = t >> 2, achk = t & 3;
    const int brow = t >> 1, bhalf = t & 1;

    for (int k0 = 0; k0 < KDIM; k0 += 32) {
        __syncthreads();
        *(uint4*)(&As[arow][achk * 8]) =
            *(const uint4*)(A + (size_t)(row0 + arow) * KDIM + k0 + achk * 8);
        const unsigned short* bsrc = BT + (size_t)(col0 + brow) * KDIM + k0 + bhalf * 16;
        *(uint4*)(&Bs[brow][bhalf * 16])     = *(const uint4*)(bsrc);
        *(uint4*)(&Bs[brow][bhalf * 16 + 8]) = *(const uint4*)(bsrc + 8);
        __syncthreads();
        bf16x8 af[2], bfr[4];
        #pragma unroll
        for (int fm = 0; fm < 2; fm++)
            af[fm] = *(const bf16x8*)(&As[wm * 32 + fm * 16 + l15][lg * 8]);
        #pragma unroll
        for (int fn = 0; fn < 4; fn++)
            bfr[fn] = *(const bf16x8*)(&Bs[wn * 64 + fn * 16 + l15][lg * 8]);
        #pragma unroll
        for (int fm = 0; fm < 2; fm++)
            #pragma unroll
            for (int fn = 0; fn < 4; fn++)
                acc[fm][fn] = __builtin_amdgcn_mfma_f32_16x16x32_bf16(
                    af[fm], bfr[fn], acc[fm][fn], 0, 0, 0);
    }
    #pragma unroll
    for (int fm = 0; fm < 2; fm++)
        #pragma unroll
        for (int fn = 0; fn < 4; fn++) {
            int col = col0 + wn * 64 + fn * 16 + l15;
            float bvv = bias[col];
            #pragma unroll
            for (int r = 0; r < 4; r++) {
                int row = row0 + wm * 32 + fm * 16 + lg * 4 + r;
                float v = acc[fm][fn][r] + bvv;
                if (RELU) v = fmaxf(v, 0.f);
                v *= scale;
                if (OUTBF) ((unsigned short*)Cout)[(size_t)row * 256 + col] = f2bf(v);
                else       ((float*)Cout)[(size_t)row * 256 + col] = v;
            }
        }
}

__global__ __launch_bounds__(256, 2) void gemm512_kernel(
    const unsigned short* __restrict__ A,
    const unsigned short* __restrict__ BT,
    const float* __restrict__ bias,
    unsigned short* __restrict__ Cout)
{
    gemm_body<512, 1, 1>(A, BT, bias, (void*)Cout, 1.0f);
}

// ---------------- Vw body: Vw[row][h] = X[row]·Wvw[:,h] + bvw[h]
static __device__ __forceinline__ void vw_body(
    const unsigned short* __restrict__ Xbf,
    const float* __restrict__ Wvw,
    const float* __restrict__ bvw,
    float* __restrict__ Vw)
{
    __shared__ float sW[2048];
    __shared__ float sb[8];
    int t = threadIdx.x;
    #pragma unroll
    for (int i = 0; i < 8; i++) sW[i * 256 + t] = Wvw[i * 256 + t];
    if (t < 8) sb[t] = bvw[t];
    __syncthreads();
    int row = blockIdx.x * 256 + t;
    float acc[8];
    #pragma unroll
    for (int h = 0; h < 8; h++) acc[h] = sb[h];
    for (int d0 = 0; d0 < 32; d0++) {
        bf16x8 x = *(const bf16x8*)(Xbf + (size_t)row * 256 + d0 * 8);
        #pragma unroll
        for (int j = 0; j < 8; j++) {
            float xf = bf2f((unsigned short)x[j]);
            #pragma unroll
            for (int h = 0; h < 8; h++) acc[h] += xf * sW[(d0 * 8 + j) * 8 + h];
        }
    }
    *(float4*)(Vw + (size_t)row * 8)     = make_float4(acc[0], acc[1], acc[2], acc[3]);
    *(float4*)(Vw + (size_t)row * 8 + 4) = make_float4(acc[4], acc[5], acc[6], acc[7]);
}

// ---------------- fused Q-GEMM / K-GEMM / Vw in one launch (z selects)
__global__ __launch_bounds__(256, 2) void gemmQKV_kernel(
    const unsigned short* __restrict__ qbf,
    const unsigned short* __restrict__ WTq,
    const float* __restrict__ bq,
    unsigned short* __restrict__ Qbf,
    const unsigned short* __restrict__ Xbf,
    const unsigned short* __restrict__ WTk,
    const float* __restrict__ bk,
    unsigned short* __restrict__ Kbf,
    const float* __restrict__ Wvw,
    const float* __restrict__ bvw,
    float* __restrict__ Vw)
{
    if (blockIdx.z == 0) {
        gemm_body<256, 0, 1>(qbf, WTq, bq, (void*)Qbf, 0.17677669529663687f);
    } else if (blockIdx.z == 1) {
        gemm_body<256, 0, 1>(Xbf, WTk, bk, (void*)Kbf, 1.0f);
    } else {
        if (blockIdx.x >= 64 || blockIdx.y != 0) return;
        vw_body(Xbf, Wvw, bvw, Vw);
    }
}

// ---------------- attnD: denominator partials -> atomicAdd into den workspace
// grid 2048: id -> b (32) x qt (16) x kc (4); 256 threads = 4 waves
__global__ __launch_bounds__(256, 8) void attnD_kernel(
    const unsigned short* __restrict__ Qbf,
    const unsigned short* __restrict__ Kbf,
    const float* __restrict__ rel,
    const float* __restrict__ tsp,
    float* __restrict__ denp,    // [32][8][512]
    float* __restrict__ dent,    // [32][512]
    float* __restrict__ denr)    // [32][512]
{
    const int t = threadIdx.x;
    const int id = blockIdx.x;
    const int b  = id >> 6;
    const int qt = (id >> 2) & 15;
    const int kc = id & 3;
    const int q0 = qt * 32;
    const int w = t >> 6, lane = t & 63;
    const int l15 = lane & 15, lg = lane >> 4;

    // Q fragments for this wave's 2 heads
    bf16x8 aq[2][2];
    #pragma unroll
    for (int hh = 0; hh < 2; hh++)
        #pragma unroll
        for (int mf = 0; mf < 2; mf++)
            aq[hh][mf] = *(const bf16x8*)(Qbf +
                (size_t)(b * SEQ + q0 + mf * 16 + l15) * EMB + (2 * w + hh) * 32 + lg * 8);

    float dp[2][2][4] = {};
    #pragma unroll 1
    for (int i = 0; i < 4; i++) {
        const int kt = kc + 4 * i;
        if (kt > qt) break;
        const int k0 = kt * 32;
        #pragma unroll
        for (int hh = 0; hh < 2; hh++) {
            #pragma unroll
            for (int nf = 0; nf < 2; nf++) {
                bf16x8 bk = *(const bf16x8*)(Kbf +
                    (size_t)(b * SEQ + k0 + nf * 16 + l15) * EMB + (2 * w + hh) * 32 + lg * 8);
                const int kcol = k0 + nf * 16 + l15;
                #pragma unroll
                for (int mf = 0; mf < 2; mf++) {
                    f32x4 am = __builtin_amdgcn_mfma_f32_16x16x32_bf16(
                        aq[hh][mf], bk, (f32x4){0, 0, 0, 0}, 0, 0, 0);
                    #pragma unroll
                    for (int r = 0; r < 4; r++) {
                        const int qrow = q0 + mf * 16 + lg * 4 + r;
                        dp[hh][mf][r] += (kcol <= qrow) ? __expf(am[r]) : 0.f;
                    }
                }
            }
        }
    }

    // rel/ts: wave w handles tile kc + 4*w
    float dt[2][4] = {}, dr[2][4] = {};
    {
        const int kt2 = kc + 4 * w;
        if (kt2 <= qt) {
            const int k0 = kt2 * 32;
            #pragma unroll
            for (int mf = 0; mf < 2; mf++)
                #pragma unroll
                for (int r = 0; r < 4; r++) {
                    const int qrow = q0 + mf * 16 + lg * 4 + r;
                    const size_t base = ((size_t)(b * SEQ) + qrow) * SEQ + k0 + l15;
                    #pragma unroll
                    for (int nf = 0; nf < 2; nf++) {
                        const int kcol = k0 + nf * 16 + l15;
                        const bool va = kcol <= qrow;
                        float tv = tsp[base + nf * 16];
                        float rv = rel[base + nf * 16];
                        dt[mf][r] += va ? __expf(__expf(-fabsf(tv))) : 0.f;
                        dr[mf][r] += (va && rv != 0.f) ? __expf(rv) : 0.f;
                    }
                }
        }
    }

    // shfl-reduce over the 16 key lanes, then atomicAdd partials
    #pragma unroll
    for (int hh = 0; hh < 2; hh++)
        #pragma unroll
        for (int mf = 0; mf < 2; mf++)
            #pragma unroll
            for (int r = 0; r < 4; r++) {
                float v = dp[hh][mf][r];
                v += __shfl_xor(v, 1); v += __shfl_xor(v, 2);
                v += __shfl_xor(v, 4); v += __shfl_xor(v, 8);
                if (l15 == 0)
                    atomicAdd(&denp[((size_t)(b * NHEAD + 2 * w + hh)) * SEQ
                                    + q0 + mf * 16 + lg * 4 + r], v);
            }
    #pragma unroll
    for (int mf = 0; mf < 2; mf++)
        #pragma unroll
        for (int r = 0; r < 4; r++) {
            float v = dt[mf][r];
            v += __shfl_xor(v, 1); v += __shfl_xor(v, 2);
            v += __shfl_xor(v, 4); v += __shfl_xor(v, 8);
            float u = dr[mf][r];
            u += __shfl_xor(u, 1); u += __shfl_xor(u, 2);
            u += __shfl_xor(u, 4); u += __shfl_xor(u, 8);
            if (l15 == 0) {
                const int qrow = q0 + mf * 16 + lg * 4 + r;
                atomicAdd(&dent[b * SEQ + qrow], v);
                atomicAdd(&denr[b * SEQ + qrow], u);
            }
        }
}

// ---------------- attnW: uniform per-tile blocks; blend + full-line writes + logits
// grid 8192: id -> b (32) x tile (256 = qt*16+kt); 256 threads = 4 waves
__global__ __launch_bounds__(256, 4) void attnW_kernel(
    const unsigned short* __restrict__ Qbf,
    const unsigned short* __restrict__ Kbf,
    const float* __restrict__ Vw,
    const float* __restrict__ rel,
    const float* __restrict__ tsp,
    const float* __restrict__ denp,
    const float* __restrict__ dent,
    const float* __restrict__ denr,
    const float* __restrict__ pl1,
    const float* __restrict__ pl2,
    float* __restrict__ logits,
    float* __restrict__ attn)
{
    __shared__ float sT[NHEAD][32][33];
    __shared__ float slog[4][32];

    const int t = threadIdx.x;
    const int id = blockIdx.x;
    const int b = id >> 8;
    const int tile = id & 255;
    const int qt = tile >> 4, kt = tile & 15;
    const int q0 = qt * 32, k0 = kt * 32;

    if (kt > qt) {   // strictly-future tile: pure zero-fill, full 128B lines
        const int h = t >> 5, row = t & 31;
        const float4 z = make_float4(0.f, 0.f, 0.f, 0.f);
        float4* p = (float4*)(attn + ((size_t)((b * NHEAD + h) * SEQ) + q0 + row) * SEQ + k0);
        #pragma unroll
        for (int c = 0; c < 8; c++) p[c] = z;
        return;
    }

    const int w = t >> 6, lane = t & 63;
    const int l15 = lane & 15, lg = lane >> 4;
    const float l1 = pl1[0], l2 = pl2[0];
    const float cp = (1.f - l1) * (1.f - l2);
    const float ct = (1.f - l1) * l2;
    const float cr = l1;

    // per-row stats + et/er in C-frag layout
    float invt[2][4], invr[2][4], et[2][4][2], er[2][4][2];
    #pragma unroll
    for (int mf = 0; mf < 2; mf++)
        #pragma unroll
        for (int r = 0; r < 4; r++) {
            const int qrow = q0 + mf * 16 + lg * 4 + r;
            float dt = dent[b * SEQ + qrow];
            float dr = denr[b * SEQ + qrow];
            invt[mf][r] = 1.f / dt;
            invr[mf][r] = dr > 0.f ? 1.f / dr : 0.f;
            const size_t base = ((size_t)(b * SEQ) + qrow) * SEQ + k0 + l15;
            #pragma unroll
            for (int nf = 0; nf < 2; nf++) {
                const int kcol = k0 + nf * 16 + l15;
                const bool va = kcol <= qrow;
                float tv = tsp[base + nf * 16];
                float rv = rel[base + nf * 16];
                et[mf][r][nf] = va ? __expf(__expf(-fabsf(tv))) : 0.f;
                er[mf][r][nf] = (va && rv != 0.f) ? __expf(rv) : 0.f;
            }
        }

    float plog[2][4] = {};
    #pragma unroll 1
    for (int hh = 0; hh < 2; hh++) {
        const int h = 2 * w + hh;
        bf16x8 aq0 = *(const bf16x8*)(Qbf + (size_t)(b * SEQ + q0 + l15) * EMB + h * 32 + lg * 8);
        bf16x8 aq1 = *(const bf16x8*)(Qbf + (size_t)(b * SEQ + q0 + 16 + l15) * EMB + h * 32 + lg * 8);
        bf16x8 bk0 = *(const bf16x8*)(Kbf + (size_t)(b * SEQ + k0 + l15) * EMB + h * 32 + lg * 8);
        bf16x8 bk1 = *(const bf16x8*)(Kbf + (size_t)(b * SEQ + k0 + 16 + l15) * EMB + h * 32 + lg * 8);
        const float vw0 = Vw[(size_t)(b * SEQ + k0 + l15) * 8 + h];
        const float vw1 = Vw[(size_t)(b * SEQ + k0 + 16 + l15) * 8 + h];
        float invp[2][4];
        #pragma unroll
        for (int mf = 0; mf < 2; mf++)
            #pragma unroll
            for (int r = 0; r < 4; r++)
                invp[mf][r] = 1.f / denp[((size_t)(b * NHEAD + h)) * SEQ
                                         + q0 + mf * 16 + lg * 4 + r];
        f32x4 am[2][2];
        am[0][0] = __builtin_amdgcn_mfma_f32_16x16x32_bf16(aq0, bk0, (f32x4){0,0,0,0}, 0, 0, 0);
        am[0][1] = __builtin_amdgcn_mfma_f32_16x16x32_bf16(aq0, bk1, (f32x4){0,0,0,0}, 0, 0, 0);
        am[1][0] = __builtin_amdgcn_mfma_f32_16x16x32_bf16(aq1, bk0, (f32x4){0,0,0,0}, 0, 0, 0);
        am[1][1] = __builtin_amdgcn_mfma_f32_16x16x32_bf16(aq1, bk1, (f32x4){0,0,0,0}, 0, 0, 0);
        #pragma unroll
        for (int nf = 0; nf < 2; nf++) {
            const int kcol = k0 + nf * 16 + l15;
            const float vwv = nf ? vw1 : vw0;
            #pragma unroll
            for (int mf = 0; mf < 2; mf++)
                #pragma unroll
                for (int r = 0; r < 4; r++) {
                    const int qloc = mf * 16 + lg * 4 + r;
                    const int qrow = q0 + qloc;
                    float a = 0.f;
                    if (kcol <= qrow)
                        a = cp * __expf(am[mf][nf][r]) * invp[mf][r]
                          + ct * et[mf][r][nf] * invt[mf][r]
                          + cr * er[mf][r][nf] * invr[mf][r];
                    sT[h][qloc][nf * 16 + l15] = a;
                    plog[mf][r] = fmaf(a, vwv, plog[mf][r]);
                }
        }
    }
    __syncthreads();

    // coalesced write-out: thread -> (head, row), full 128B line per row
    {
        const int h2 = t >> 5, row2 = t & 31;
        const float* srow = &sT[h2][row2][0];
        float* dst = attn + ((size_t)((b * NHEAD + h2) * SEQ) + q0 + row2) * SEQ + k0;
        #pragma unroll
        for (int c4 = 0; c4 < 8; c4++) {
            float4 v = make_float4(srow[c4 * 4], srow[c4 * 4 + 1],
                                   srow[c4 * 4 + 2], srow[c4 * 4 + 3]);
            *(float4*)(dst + c4 * 4) = v;
        }
    }

    // logits partial: reduce over key lanes, cross-wave via LDS, one atomic per row
    #pragma unroll
    for (int mf = 0; mf < 2; mf++)
        #pragma unroll
        for (int r = 0; r < 4; r++) {
            float v = plog[mf][r];
            v += __shfl_xor(v, 1); v += __shfl_xor(v, 2);
            v += __shfl_xor(v, 4); v += __shfl_xor(v, 8);
            if (l15 == 0) slog[w][mf * 16 + lg * 4 + r] = v;
        }
    __syncthreads();
    if (t < 32)
        atomicAdd(&logits[b * SEQ + q0 + t],
                  slog[0][t] + slog[1][t] + slog[2][t] + slog[3][t]);
}

// ---------------- host launch ----------------
extern "C" void kernel_launch(void* const* d_in, const int* in_sizes, int n_in,
                              void* d_out, int out_size, void* d_ws, size_t ws_size,
                              hipStream_t stream)
{
    (void)in_sizes; (void)n_in; (void)out_size; (void)ws_size;
    const int*   item_inputs  = (const int*)d_in[0];
    const int*   label_inputs = (const int*)d_in[1];
    const int*   item_ids     = (const int*)d_in[2];
    const float* rel   = (const float*)d_in[3];
    const float* tsp   = (const float*)d_in[4];
    const float* emb   = (const float*)d_in[5];
    const float* W_in  = (const float*)d_in[6];
    const float* b_in  = (const float*)d_in[7];
    const float* Wq    = (const float*)d_in[8];
    const float* bq    = (const float*)d_in[9];
    const float* Wk    = (const float*)d_in[10];
    const float* bk    = (const float*)d_in[11];
    const float* Wv    = (const float*)d_in[12];
    const float* bv    = (const float*)d_in[13];
    const float* Wout  = (const float*)d_in[14];
    const float* bout  = (const float*)d_in[15];
    const float* l1    = (const float*)d_in[16];
    const float* l2    = (const float*)d_in[17];

    const size_t R = 16384;
    char* w = (char*)d_ws;
    unsigned short* Abig = (unsigned short*)w; w += R * 512 * 2;
    unsigned short* qbf  = (unsigned short*)w; w += R * 256 * 2;
    unsigned short* WTin = (unsigned short*)w; w += (size_t)256 * 512 * 2;
    unsigned short* WTq  = (unsigned short*)w; w += (size_t)256 * 256 * 2;
    unsigned short* WTk  = (unsigned short*)w; w += (size_t)256 * 256 * 2;
    unsigned short* Xbf  = (unsigned short*)w; w += R * 256 * 2;
    unsigned short* Qbf  = (unsigned short*)w; w += R * 256 * 2;
    unsigned short* Kbf  = (unsigned short*)w; w += R * 256 * 2;
    float* Wvw  = (float*)w; w += 2048 * 4;
    float* Vw   = (float*)w; w += R * 8 * 4;
    float* bvw  = (float*)w; w += 256;          // 8 floats + pad
    float* denp = (float*)w; w += (size_t)32 * NHEAD * SEQ * 4;   // 512 KB
    float* dent = (float*)w; w += (size_t)32 * SEQ * 4;           // 64 KB
    float* denr = (float*)w; w += (size_t)32 * SEQ * 4;           // 64 KB

    // zero den workspace (contiguous: denp, dent, denr)
    hipMemsetAsync(denp, 0, ((size_t)32 * NHEAD * SEQ + 2 * 32 * SEQ) * 4, stream);

    prep_kernel<<<dim3(8192), dim3(256), 0, stream>>>(
        item_inputs, label_inputs, item_ids, emb, Abig, qbf);
    wcombo_kernel<<<dim3(1097), dim3(256), 0, stream>>>(
        W_in, Wq, Wk, Wv, Wout, bv, bout, WTin, WTq, WTk, Wvw, bvw, (float*)d_out);

    gemm512_kernel<<<dim3(256, 2), dim3(256), 0, stream>>>(Abig, WTin, b_in, Xbf);
    gemmQKV_kernel<<<dim3(256, 2, 3), dim3(256), 0, stream>>>(
        qbf, WTq, bq, Qbf, Xbf, WTk, bk, Kbf, Wvw, bvw, Vw);

    float* logits = (float*)d_out;
    float* attnp  = (float*)d_out + 16384;
    attnD_kernel<<<dim3(2048), dim3(256), 0, stream>>>(
        Qbf, Kbf, rel, tsp, denp, dent, denr);
    attnW_kernel<<<dim3(8192), dim3(256), 0, stream>>>(
        Qbf, Kbf, Vw, rel, tsp, denp, dent, denr, l1, l2, logits, attnp);
}

// Round 5
// 211.561 us; speedup vs baseline: 1.1842x; 1.1842x over previous
//
#include <hip/hip_runtime.h>
#include <hip/hip_bf16.h>

#define SEQ 512
#define EMB 256
#define NHEAD 8
#define HD 32

using bf16x8 = __attribute__((ext_vector_type(8))) short;
using f32x4  = __attribute__((ext_vector_type(4))) float;

static __device__ __forceinline__ unsigned short f2bf(float x) {
    union { float f; unsigned int u; } v; v.f = x;
    unsigned int r = v.u + 0x7FFFu + ((v.u >> 16) & 1u);
    return (unsigned short)(r >> 16);
}
static __device__ __forceinline__ float bf2f(unsigned short v) {
    union { unsigned int u; float f; } w; w.u = ((unsigned int)v) << 16; return w.f;
}

// ---------------- prep: gather embeds, build masked-concat A (bf16) + query (bf16)
// grid 4096 x 256: thread handles 4 cols of one row
__global__ __launch_bounds__(256) void prep_kernel(
    const int* __restrict__ item_inputs,
    const int* __restrict__ label_inputs,
    const int* __restrict__ item_ids,
    const float* __restrict__ embeds,
    unsigned short* __restrict__ Abig,   // 16384 x 512 bf16
    unsigned short* __restrict__ qbf)    // 16384 x 256 bf16
{
    int t = threadIdx.x;
    int r = blockIdx.x * 4 + (t >> 6);
    int j = (t & 63) * 4;
    int item = item_inputs[r];
    int lab  = label_inputs[r];
    int qid  = item_ids[r];
    float4 e4 = *(const float4*)(embeds + (size_t)item * EMB + j);
    ushort4 on  = make_ushort4(f2bf(e4.x), f2bf(e4.y), f2bf(e4.z), f2bf(e4.w));
    ushort4 off = make_ushort4(0, 0, 0, 0);
    *(ushort4*)(Abig + (size_t)r * 512 + j)       = lab ? on : off;
    *(ushort4*)(Abig + (size_t)r * 512 + 256 + j) = lab ? off : on;
    float4 q4 = *(const float4*)(embeds + (size_t)qid * EMB + j);
    *(ushort4*)(qbf + (size_t)r * 256 + j) =
        make_ushort4(f2bf(q4.x), f2bf(q4.y), f2bf(q4.z), f2bf(q4.w));
}

// ---------------- merged weight prep + logits init
__global__ __launch_bounds__(256) void wcombo_kernel(
    const float* __restrict__ W_in,
    const float* __restrict__ Wq,
    const float* __restrict__ Wk,
    const float* __restrict__ Wv,
    const float* __restrict__ Wout,
    const float* __restrict__ bv,
    const float* __restrict__ bout,
    unsigned short* __restrict__ WTin,   // 256 x 512
    unsigned short* __restrict__ WTq,    // 256 x 256
    unsigned short* __restrict__ WTk,    // 256 x 256
    float* __restrict__ Wvw,             // 256 x 8
    float* __restrict__ bvw,             // 8
    float* __restrict__ logits)          // init to bout
{
    int idx = blockIdx.x * 256 + threadIdx.x;
    if (idx < 131072) {                       // WTin[n][k] = W_in[k][n], K=512
        int n = idx >> 9, k = idx & 511;
        WTin[idx] = f2bf(W_in[(size_t)k * 256 + n]);
    } else if (idx < 196608) {                // WTq, K=256
        int i = idx - 131072;
        int n = i >> 8, k = i & 255;
        WTq[i] = f2bf(Wq[(size_t)k * 256 + n]);
    } else if (idx < 262144) {                // WTk, K=256
        int i = idx - 196608;
        int n = i >> 8, k = i & 255;
        WTk[i] = f2bf(Wk[(size_t)k * 256 + n]);
    } else if (idx < 264192) {                // Wvw[c][h] = sum_d Wv[c][32h+d]*Wout[32h+d]
        int i = idx - 262144;
        int c = i >> 3, h = i & 7;
        float s = 0.f;
        #pragma unroll
        for (int d = 0; d < 32; d++) s += Wv[(size_t)c * 256 + h * 32 + d] * Wout[h * 32 + d];
        Wvw[i] = s;
    } else if (idx < 264200) {                // bvw[h]
        int h = idx - 264192;
        float s = 0.f;
        #pragma unroll
        for (int d = 0; d < 32; d++) s += bv[h * 32 + d] * Wout[h * 32 + d];
        bvw[h] = s;
    } else if (idx < 280584) {                // logits init = bout
        logits[idx - 264200] = bout[0];
    }
}

// ---------------- MFMA GEMM body: C(M x 256) = A(M x KDIM) * BT^T + bias
template<int KDIM, int RELU, int OUTBF>
static __device__ __forceinline__ void gemm_body(
    const unsigned short* __restrict__ A,
    const unsigned short* __restrict__ BT,
    const float* __restrict__ bias,
    void* __restrict__ Cout, float scale)
{
    __shared__ unsigned short As[64][40];
    __shared__ unsigned short Bs[128][40];
    const int t = threadIdx.x;
    const int row0 = blockIdx.x * 64;
    const int col0 = blockIdx.y * 128;
    const int wid = t >> 6, lane = t & 63;
    const int wm = wid & 1, wn = wid >> 1;
    const int lg = lane >> 4, l15 = lane & 15;

    f32x4 acc[2][4];
    #pragma unroll
    for (int i = 0; i < 2; i++)
        #pragma unroll
        for (int j = 0; j < 4; j++) acc[i][j] = (f32x4){0.f, 0.f, 0.f, 0.f};

    const int arow = t >> 2, achk = t & 3;
    const int brow = t >> 1, bhalf = t & 1;

    for (int k0 = 0; k0 < KDIM; k0 += 32) {
        __syncthreads();
        *(uint4*)(&As[arow][achk * 8]) =
            *(const uint4*)(A + (size_t)(row0 + arow) * KDIM + k0 + achk * 8);
        const unsigned short* bsrc = BT + (size_t)(col0 + brow) * KDIM + k0 + bhalf * 16;
        *(uint4*)(&Bs[brow][bhalf * 16])     = *(const uint4*)(bsrc);
        *(uint4*)(&Bs[brow][bhalf * 16 + 8]) = *(const uint4*)(bsrc + 8);
        __syncthreads();
        bf16x8 af[2], bfr[4];
        #pragma unroll
        for (int fm = 0; fm < 2; fm++)
            af[fm] = *(const bf16x8*)(&As[wm * 32 + fm * 16 + l15][lg * 8]);
        #pragma unroll
        for (int fn = 0; fn < 4; fn++)
            bfr[fn] = *(const bf16x8*)(&Bs[wn * 64 + fn * 16 + l15][lg * 8]);
        #pragma unroll
        for (int fm = 0; fm < 2; fm++)
            #pragma unroll
            for (int fn = 0; fn < 4; fn++)
                acc[fm][fn] = __builtin_amdgcn_mfma_f32_16x16x32_bf16(
                    af[fm], bfr[fn], acc[fm][fn], 0, 0, 0);
    }
    #pragma unroll
    for (int fm = 0; fm < 2; fm++)
        #pragma unroll
        for (int fn = 0; fn < 4; fn++) {
            int col = col0 + wn * 64 + fn * 16 + l15;
            float bvv = bias[col];
            #pragma unroll
            for (int r = 0; r < 4; r++) {
                int row = row0 + wm * 32 + fm * 16 + lg * 4 + r;
                float v = acc[fm][fn][r] + bvv;
                if (RELU) v = fmaxf(v, 0.f);
                v *= scale;
                if (OUTBF) ((unsigned short*)Cout)[(size_t)row * 256 + col] = f2bf(v);
                else       ((float*)Cout)[(size_t)row * 256 + col] = v;
            }
        }
}

__global__ __launch_bounds__(256, 2) void gemm512_kernel(
    const unsigned short* __restrict__ A,
    const unsigned short* __restrict__ BT,
    const float* __restrict__ bias,
    unsigned short* __restrict__ Cout)
{
    gemm_body<512, 1, 1>(A, BT, bias, (void*)Cout, 1.0f);
}

// ---------------- Vw body: Vw[row][h] = X[row]·Wvw[:,h] + bvw[h]
static __device__ __forceinline__ void vw_body(
    const unsigned short* __restrict__ Xbf,
    const float* __restrict__ Wvw,
    const float* __restrict__ bvw,
    float* __restrict__ Vw)
{
    __shared__ float sW[2048];
    __shared__ float sb[8];
    int t = threadIdx.x;
    #pragma unroll
    for (int i = 0; i < 8; i++) sW[i * 256 + t] = Wvw[i * 256 + t];
    if (t < 8) sb[t] = bvw[t];
    __syncthreads();
    int row = blockIdx.x * 256 + t;
    float acc[8];
    #pragma unroll
    for (int h = 0; h < 8; h++) acc[h] = sb[h];
    for (int d0 = 0; d0 < 32; d0++) {
        bf16x8 x = *(const bf16x8*)(Xbf + (size_t)row * 256 + d0 * 8);
        #pragma unroll
        for (int j = 0; j < 8; j++) {
            float xf = bf2f((unsigned short)x[j]);
            #pragma unroll
            for (int h = 0; h < 8; h++) acc[h] += xf * sW[(d0 * 8 + j) * 8 + h];
        }
    }
    *(float4*)(Vw + (size_t)row * 8)     = make_float4(acc[0], acc[1], acc[2], acc[3]);
    *(float4*)(Vw + (size_t)row * 8 + 4) = make_float4(acc[4], acc[5], acc[6], acc[7]);
}

// ---------------- fused Q-GEMM / K-GEMM / Vw in one launch (z selects)
__global__ __launch_bounds__(256, 2) void gemmQKV_kernel(
    const unsigned short* __restrict__ qbf,
    const unsigned short* __restrict__ WTq,
    const float* __restrict__ bq,
    unsigned short* __restrict__ Qbf,
    const unsigned short* __restrict__ Xbf,
    const unsigned short* __restrict__ WTk,
    const float* __restrict__ bk,
    unsigned short* __restrict__ Kbf,
    const float* __restrict__ Wvw,
    const float* __restrict__ bvw,
    float* __restrict__ Vw)
{
    if (blockIdx.z == 0) {
        gemm_body<256, 0, 1>(qbf, WTq, bq, (void*)Qbf, 0.17677669529663687f);
    } else if (blockIdx.z == 1) {
        gemm_body<256, 0, 1>(Xbf, WTk, bk, (void*)Kbf, 1.0f);
    } else {
        if (blockIdx.x >= 64 || blockIdx.y != 0) return;
        vw_body(Xbf, Wvw, bvw, Vw);
    }
}

// ---------------- attnD: denominator partials -> atomicAdd into den workspace
// grid 2048: id -> b (32) x qt (16) x kc (4); 256 threads = 4 waves
__global__ __launch_bounds__(256, 8) void attnD_kernel(
    const unsigned short* __restrict__ Qbf,
    const unsigned short* __restrict__ Kbf,
    const float* __restrict__ rel,
    const float* __restrict__ tsp,
    float* __restrict__ denp,    // [32][8][512]
    float* __restrict__ dent,    // [32][512]
    float* __restrict__ denr)    // [32][512]
{
    const int t = threadIdx.x;
    const int id = blockIdx.x;
    const int b  = id >> 6;
    const int qt = (id >> 2) & 15;
    const int kc = id & 3;
    const int q0 = qt * 32;
    const int w = t >> 6, lane = t & 63;
    const int l15 = lane & 15, lg = lane >> 4;

    // Q fragments for this wave's 2 heads
    bf16x8 aq[2][2];
    #pragma unroll
    for (int hh = 0; hh < 2; hh++)
        #pragma unroll
        for (int mf = 0; mf < 2; mf++)
            aq[hh][mf] = *(const bf16x8*)(Qbf +
                (size_t)(b * SEQ + q0 + mf * 16 + l15) * EMB + (2 * w + hh) * 32 + lg * 8);

    float dp[2][2][4] = {};
    #pragma unroll 1
    for (int i = 0; i < 4; i++) {
        const int kt = kc + 4 * i;
        if (kt > qt) break;
        const int k0 = kt * 32;
        #pragma unroll
        for (int hh = 0; hh < 2; hh++) {
            #pragma unroll
            for (int nf = 0; nf < 2; nf++) {
                bf16x8 bk = *(const bf16x8*)(Kbf +
                    (size_t)(b * SEQ + k0 + nf * 16 + l15) * EMB + (2 * w + hh) * 32 + lg * 8);
                const int kcol = k0 + nf * 16 + l15;
                #pragma unroll
                for (int mf = 0; mf < 2; mf++) {
                    f32x4 am = __builtin_amdgcn_mfma_f32_16x16x32_bf16(
                        aq[hh][mf], bk, (f32x4){0, 0, 0, 0}, 0, 0, 0);
                    #pragma unroll
                    for (int r = 0; r < 4; r++) {
                        const int qrow = q0 + mf * 16 + lg * 4 + r;
                        dp[hh][mf][r] += (kcol <= qrow) ? __expf(am[r]) : 0.f;
                    }
                }
            }
        }
    }

    // rel/ts: wave w handles tile kc + 4*w
    float dt[2][4] = {}, dr[2][4] = {};
    {
        const int kt2 = kc + 4 * w;
        if (kt2 <= qt) {
            const int k0 = kt2 * 32;
            #pragma unroll
            for (int mf = 0; mf < 2; mf++)
                #pragma unroll
                for (int r = 0; r < 4; r++) {
                    const int qrow = q0 + mf * 16 + lg * 4 + r;
                    const size_t base = ((size_t)(b * SEQ) + qrow) * SEQ + k0 + l15;
                    #pragma unroll
                    for (int nf = 0; nf < 2; nf++) {
                        const int kcol = k0 + nf * 16 + l15;
                        const bool va = kcol <= qrow;
                        float tv = tsp[base + nf * 16];
                        float rv = rel[base + nf * 16];
                        dt[mf][r] += va ? __expf(__expf(-fabsf(tv))) : 0.f;
                        dr[mf][r] += (va && rv != 0.f) ? __expf(rv) : 0.f;
                    }
                }
        }
    }

    // shfl-reduce over the 16 key lanes, then atomicAdd partials
    #pragma unroll
    for (int hh = 0; hh < 2; hh++)
        #pragma unroll
        for (int mf = 0; mf < 2; mf++)
            #pragma unroll
            for (int r = 0; r < 4; r++) {
                float v = dp[hh][mf][r];
                v += __shfl_xor(v, 1); v += __shfl_xor(v, 2);
                v += __shfl_xor(v, 4); v += __shfl_xor(v, 8);
                if (l15 == 0)
                    atomicAdd(&denp[((size_t)(b * NHEAD + 2 * w + hh)) * SEQ
                                    + q0 + mf * 16 + lg * 4 + r], v);
            }
    #pragma unroll
    for (int mf = 0; mf < 2; mf++)
        #pragma unroll
        for (int r = 0; r < 4; r++) {
            float v = dt[mf][r];
            v += __shfl_xor(v, 1); v += __shfl_xor(v, 2);
            v += __shfl_xor(v, 4); v += __shfl_xor(v, 8);
            float u = dr[mf][r];
            u += __shfl_xor(u, 1); u += __shfl_xor(u, 2);
            u += __shfl_xor(u, 4); u += __shfl_xor(u, 8);
            if (l15 == 0) {
                const int qrow = q0 + mf * 16 + lg * 4 + r;
                atomicAdd(&dent[b * SEQ + qrow], v);
                atomicAdd(&denr[b * SEQ + qrow], u);
            }
        }
}

// ---------------- attnW: uniform per-tile blocks; blend + LANE-coalesced writes
// grid 8192: id -> b (32) x tile (256 = qt*16+kt); 256 threads = 4 waves
__global__ __launch_bounds__(256, 4) void attnW_kernel(
    const unsigned short* __restrict__ Qbf,
    const unsigned short* __restrict__ Kbf,
    const float* __restrict__ Vw,
    const float* __restrict__ rel,
    const float* __restrict__ tsp,
    const float* __restrict__ denp,
    const float* __restrict__ dent,
    const float* __restrict__ denr,
    const float* __restrict__ pl1,
    const float* __restrict__ pl2,
    float* __restrict__ logits,
    float* __restrict__ attn)
{
    __shared__ float sT[NHEAD][32][33];
    __shared__ float slog[4][32];

    const int t = threadIdx.x;
    const int id = blockIdx.x;
    const int b = id >> 8;
    const int tile = id & 255;
    const int qt = tile >> 4, kt = tile & 15;
    const int q0 = qt * 32, k0 = kt * 32;

    // lane-coalesced write geometry: 8 lanes cover one full 128B row segment
    const int row_g = t >> 3;     // 0..31 concurrent row slot
    const int col4  = (t & 7) * 4;

    if (kt > qt) {   // strictly-future tile: zero-fill, 8 consecutive lanes per line
        const float4 z = make_float4(0.f, 0.f, 0.f, 0.f);
        #pragma unroll
        for (int step = 0; step < 8; step++) {
            const int ridx = step * 32 + row_g;       // 0..255
            const int h = ridx >> 5, qloc = ridx & 31;
            *(float4*)(attn + ((size_t)((b * NHEAD + h) * SEQ) + q0 + qloc) * SEQ
                       + k0 + col4) = z;
        }
        return;
    }

    const int w = t >> 6, lane = t & 63;
    const int l15 = lane & 15, lg = lane >> 4;
    const float l1 = pl1[0], l2 = pl2[0];
    const float cp = (1.f - l1) * (1.f - l2);
    const float ct = (1.f - l1) * l2;
    const float cr = l1;

    // per-row stats + et/er in C-frag layout
    float invt[2][4], invr[2][4], et[2][4][2], er[2][4][2];
    #pragma unroll
    for (int mf = 0; mf < 2; mf++)
        #pragma unroll
        for (int r = 0; r < 4; r++) {
            const int qrow = q0 + mf * 16 + lg * 4 + r;
            float dt = dent[b * SEQ + qrow];
            float dr = denr[b * SEQ + qrow];
            invt[mf][r] = 1.f / dt;
            invr[mf][r] = dr > 0.f ? 1.f / dr : 0.f;
            const size_t base = ((size_t)(b * SEQ) + qrow) * SEQ + k0 + l15;
            #pragma unroll
            for (int nf = 0; nf < 2; nf++) {
                const int kcol = k0 + nf * 16 + l15;
                const bool va = kcol <= qrow;
                float tv = tsp[base + nf * 16];
                float rv = rel[base + nf * 16];
                et[mf][r][nf] = va ? __expf(__expf(-fabsf(tv))) : 0.f;
                er[mf][r][nf] = (va && rv != 0.f) ? __expf(rv) : 0.f;
            }
        }

    float plog[2][4] = {};
    #pragma unroll 1
    for (int hh = 0; hh < 2; hh++) {
        const int h = 2 * w + hh;
        bf16x8 aq0 = *(const bf16x8*)(Qbf + (size_t)(b * SEQ + q0 + l15) * EMB + h * 32 + lg * 8);
        bf16x8 aq1 = *(const bf16x8*)(Qbf + (size_t)(b * SEQ + q0 + 16 + l15) * EMB + h * 32 + lg * 8);
        bf16x8 bk0 = *(const bf16x8*)(Kbf + (size_t)(b * SEQ + k0 + l15) * EMB + h * 32 + lg * 8);
        bf16x8 bk1 = *(const bf16x8*)(Kbf + (size_t)(b * SEQ + k0 + 16 + l15) * EMB + h * 32 + lg * 8);
        const float vw0 = Vw[(size_t)(b * SEQ + k0 + l15) * 8 + h];
        const float vw1 = Vw[(size_t)(b * SEQ + k0 + 16 + l15) * 8 + h];
        float invp[2][4];
        #pragma unroll
        for (int mf = 0; mf < 2; mf++)
            #pragma unroll
            for (int r = 0; r < 4; r++)
                invp[mf][r] = 1.f / denp[((size_t)(b * NHEAD + h)) * SEQ
                                         + q0 + mf * 16 + lg * 4 + r];
        f32x4 am[2][2];
        am[0][0] = __builtin_amdgcn_mfma_f32_16x16x32_bf16(aq0, bk0, (f32x4){0,0,0,0}, 0, 0, 0);
        am[0][1] = __builtin_amdgcn_mfma_f32_16x16x32_bf16(aq0, bk1, (f32x4){0,0,0,0}, 0, 0, 0);
        am[1][0] = __builtin_amdgcn_mfma_f32_16x16x32_bf16(aq1, bk0, (f32x4){0,0,0,0}, 0, 0, 0);
        am[1][1] = __builtin_amdgcn_mfma_f32_16x16x32_bf16(aq1, bk1, (f32x4){0,0,0,0}, 0, 0, 0);
        #pragma unroll
        for (int nf = 0; nf < 2; nf++) {
            const int kcol = k0 + nf * 16 + l15;
            const float vwv = nf ? vw1 : vw0;
            #pragma unroll
            for (int mf = 0; mf < 2; mf++)
                #pragma unroll
                for (int r = 0; r < 4; r++) {
                    const int qloc = mf * 16 + lg * 4 + r;
                    const int qrow = q0 + qloc;
                    float a = 0.f;
                    if (kcol <= qrow)
                        a = cp * __expf(am[mf][nf][r]) * invp[mf][r]
                          + ct * et[mf][r][nf] * invt[mf][r]
                          + cr * er[mf][r][nf] * invr[mf][r];
                    sT[h][qloc][nf * 16 + l15] = a;
                    plog[mf][r] = fmaf(a, vwv, plog[mf][r]);
                }
        }
    }
    __syncthreads();

    // lane-coalesced write-out: each step stores 8 full contiguous 128B lines
    #pragma unroll
    for (int step = 0; step < 8; step++) {
        const int ridx = step * 32 + row_g;           // 0..255
        const int h = ridx >> 5, qloc = ridx & 31;
        const float* s = &sT[h][qloc][col4];
        *(float4*)(attn + ((size_t)((b * NHEAD + h) * SEQ) + q0 + qloc) * SEQ
                   + k0 + col4) = make_float4(s[0], s[1], s[2], s[3]);
    }

    // logits partial: reduce over key lanes, cross-wave via LDS, one atomic per row
    #pragma unroll
    for (int mf = 0; mf < 2; mf++)
        #pragma unroll
        for (int r = 0; r < 4; r++) {
            float v = plog[mf][r];
            v += __shfl_xor(v, 1); v += __shfl_xor(v, 2);
            v += __shfl_xor(v, 4); v += __shfl_xor(v, 8);
            if (l15 == 0) slog[w][mf * 16 + lg * 4 + r] = v;
        }
    __syncthreads();
    if (t < 32)
        atomicAdd(&logits[b * SEQ + q0 + t],
                  slog[0][t] + slog[1][t] + slog[2][t] + slog[3][t]);
}

// ---------------- host launch ----------------
extern "C" void kernel_launch(void* const* d_in, const int* in_sizes, int n_in,
                              void* d_out, int out_size, void* d_ws, size_t ws_size,
                              hipStream_t stream)
{
    (void)in_sizes; (void)n_in; (void)out_size; (void)ws_size;
    const int*   item_inputs  = (const int*)d_in[0];
    const int*   label_inputs = (const int*)d_in[1];
    const int*   item_ids     = (const int*)d_in[2];
    const float* rel   = (const float*)d_in[3];
    const float* tsp   = (const float*)d_in[4];
    const float* emb   = (const float*)d_in[5];
    const float* W_in  = (const float*)d_in[6];
    const float* b_in  = (const float*)d_in[7];
    const float* Wq    = (const float*)d_in[8];
    const float* bq    = (const float*)d_in[9];
    const float* Wk    = (const float*)d_in[10];
    const float* bk    = (const float*)d_in[11];
    const float* Wv    = (const float*)d_in[12];
    const float* bv    = (const float*)d_in[13];
    const float* Wout  = (const float*)d_in[14];
    const float* bout  = (const float*)d_in[15];
    const float* l1    = (const float*)d_in[16];
    const float* l2    = (const float*)d_in[17];

    const size_t R = 16384;
    char* w = (char*)d_ws;
    unsigned short* Abig = (unsigned short*)w; w += R * 512 * 2;
    unsigned short* qbf  = (unsigned short*)w; w += R * 256 * 2;
    unsigned short* WTin = (unsigned short*)w; w += (size_t)256 * 512 * 2;
    unsigned short* WTq  = (unsigned short*)w; w += (size_t)256 * 256 * 2;
    unsigned short* WTk  = (unsigned short*)w; w += (size_t)256 * 256 * 2;
    unsigned short* Xbf  = (unsigned short*)w; w += R * 256 * 2;
    unsigned short* Qbf  = (unsigned short*)w; w += R * 256 * 2;
    unsigned short* Kbf  = (unsigned short*)w; w += R * 256 * 2;
    float* Wvw  = (float*)w; w += 2048 * 4;
    float* Vw   = (float*)w; w += R * 8 * 4;
    float* bvw  = (float*)w; w += 256;          // 8 floats + pad
    float* denp = (float*)w; w += (size_t)32 * NHEAD * SEQ * 4;   // 512 KB
    float* dent = (float*)w; w += (size_t)32 * SEQ * 4;           // 64 KB
    float* denr = (float*)w; w += (size_t)32 * SEQ * 4;           // 64 KB

    // zero den workspace (contiguous: denp, dent, denr)
    hipMemsetAsync(denp, 0, ((size_t)32 * NHEAD * SEQ + 2 * 32 * SEQ) * 4, stream);

    prep_kernel<<<dim3(4096), dim3(256), 0, stream>>>(
        item_inputs, label_inputs, item_ids, emb, Abig, qbf);
    wcombo_kernel<<<dim3(1097), dim3(256), 0, stream>>>(
        W_in, Wq, Wk, Wv, Wout, bv, bout, WTin, WTq, WTk, Wvw, bvw, (float*)d_out);

    gemm512_kernel<<<dim3(256, 2), dim3(256), 0, stream>>>(Abig, WTin, b_in, Xbf);
    gemmQKV_kernel<<<dim3(256, 2, 3), dim3(256), 0, stream>>>(
        qbf, WTq, bq, Qbf, Xbf, WTk, bk, Kbf, Wvw, bvw, Vw);

    float* logits = (float*)d_out;
    float* attnp  = (float*)d_out + 16384;
    attnD_kernel<<<dim3(2048), dim3(256), 0, stream>>>(
        Qbf, Kbf, rel, tsp, denp, dent, denr);
    attnW_kernel<<<dim3(8192), dim3(256), 0, stream>>>(
        Qbf, Kbf, Vw, rel, tsp, denp, dent, denr, l1, l2, logits, attnp);
}

// Round 6
// 209.696 us; speedup vs baseline: 1.1947x; 1.0089x over previous
//
#include <hip/hip_runtime.h>
#include <hip/hip_bf16.h>

#define SEQ 512
#define EMB 256
#define NHEAD 8
#define HD 32

using bf16x8 = __attribute__((ext_vector_type(8))) short;
using f32x4  = __attribute__((ext_vector_type(4))) float;

static __device__ __forceinline__ unsigned short f2bf(float x) {
    union { float f; unsigned int u; } v; v.f = x;
    unsigned int r = v.u + 0x7FFFu + ((v.u >> 16) & 1u);
    return (unsigned short)(r >> 16);
}
static __device__ __forceinline__ float bf2f(unsigned short v) {
    union { unsigned int u; float f; } w; w.u = ((unsigned int)v) << 16; return w.f;
}

// ---------------- prep: gather embeds, build masked-concat A (bf16) + query (bf16)
// grid 4096 x 256: thread handles 4 cols of one row
__global__ __launch_bounds__(256) void prep_kernel(
    const int* __restrict__ item_inputs,
    const int* __restrict__ label_inputs,
    const int* __restrict__ item_ids,
    const float* __restrict__ embeds,
    unsigned short* __restrict__ Abig,   // 16384 x 512 bf16
    unsigned short* __restrict__ qbf)    // 16384 x 256 bf16
{
    int t = threadIdx.x;
    int r = blockIdx.x * 4 + (t >> 6);
    int j = (t & 63) * 4;
    int item = item_inputs[r];
    int lab  = label_inputs[r];
    int qid  = item_ids[r];
    float4 e4 = *(const float4*)(embeds + (size_t)item * EMB + j);
    ushort4 on  = make_ushort4(f2bf(e4.x), f2bf(e4.y), f2bf(e4.z), f2bf(e4.w));
    ushort4 off = make_ushort4(0, 0, 0, 0);
    *(ushort4*)(Abig + (size_t)r * 512 + j)       = lab ? on : off;
    *(ushort4*)(Abig + (size_t)r * 512 + 256 + j) = lab ? off : on;
    float4 q4 = *(const float4*)(embeds + (size_t)qid * EMB + j);
    *(ushort4*)(qbf + (size_t)r * 256 + j) =
        make_ushort4(f2bf(q4.x), f2bf(q4.y), f2bf(q4.z), f2bf(q4.w));
}

// ---------------- merged weight prep + logits init + den-workspace zeroing
__global__ __launch_bounds__(256) void wcombo_kernel(
    const float* __restrict__ W_in,
    const float* __restrict__ Wq,
    const float* __restrict__ Wk,
    const float* __restrict__ Wv,
    const float* __restrict__ Wout,
    const float* __restrict__ bv,
    const float* __restrict__ bout,
    unsigned short* __restrict__ WTin,   // 256 x 512
    unsigned short* __restrict__ WTq,    // 256 x 256
    unsigned short* __restrict__ WTk,    // 256 x 256
    float* __restrict__ Wvw,             // 256 x 8
    float* __restrict__ bvw,             // 8
    float* __restrict__ logits,          // init to bout
    float* __restrict__ denbuf)          // 163840 floats -> zero
{
    int idx = blockIdx.x * 256 + threadIdx.x;
    if (idx < 131072) {                       // WTin[n][k] = W_in[k][n], K=512
        int n = idx >> 9, k = idx & 511;
        WTin[idx] = f2bf(W_in[(size_t)k * 256 + n]);
    } else if (idx < 196608) {                // WTq, K=256
        int i = idx - 131072;
        int n = i >> 8, k = i & 255;
        WTq[i] = f2bf(Wq[(size_t)k * 256 + n]);
    } else if (idx < 262144) {                // WTk, K=256
        int i = idx - 196608;
        int n = i >> 8, k = i & 255;
        WTk[i] = f2bf(Wk[(size_t)k * 256 + n]);
    } else if (idx < 264192) {                // Wvw[c][h] = sum_d Wv[c][32h+d]*Wout[32h+d]
        int i = idx - 262144;
        int c = i >> 3, h = i & 7;
        float s = 0.f;
        #pragma unroll
        for (int d = 0; d < 32; d++) s += Wv[(size_t)c * 256 + h * 32 + d] * Wout[h * 32 + d];
        Wvw[i] = s;
    } else if (idx < 264200) {                // bvw[h]
        int h = idx - 264192;
        float s = 0.f;
        #pragma unroll
        for (int d = 0; d < 32; d++) s += bv[h * 32 + d] * Wout[h * 32 + d];
        bvw[h] = s;
    } else if (idx < 280584) {                // logits init = bout
        logits[idx - 264200] = bout[0];
    } else if (idx < 444424) {                // zero denp/dent/denr (contiguous)
        denbuf[idx - 280584] = 0.f;
    }
}

// ---------------- MFMA GEMM body: C(M x 256) = A(M x KDIM) * BT^T + bias
template<int KDIM, int RELU, int OUTBF>
static __device__ __forceinline__ void gemm_body(
    const unsigned short* __restrict__ A,
    const unsigned short* __restrict__ BT,
    const float* __restrict__ bias,
    void* __restrict__ Cout, float scale)
{
    __shared__ unsigned short As[64][40];
    __shared__ unsigned short Bs[128][40];
    const int t = threadIdx.x;
    const int row0 = blockIdx.x * 64;
    const int col0 = blockIdx.y * 128;
    const int wid = t >> 6, lane = t & 63;
    const int wm = wid & 1, wn = wid >> 1;
    const int lg = lane >> 4, l15 = lane & 15;

    f32x4 acc[2][4];
    #pragma unroll
    for (int i = 0; i < 2; i++)
        #pragma unroll
        for (int j = 0; j < 4; j++) acc[i][j] = (f32x4){0.f, 0.f, 0.f, 0.f};

    const int arow = t >> 2, achk = t & 3;
    const int brow = t >> 1, bhalf = t & 1;

    for (int k0 = 0; k0 < KDIM; k0 += 32) {
        __syncthreads();
        *(uint4*)(&As[arow][achk * 8]) =
            *(const uint4*)(A + (size_t)(row0 + arow) * KDIM + k0 + achk * 8);
        const unsigned short* bsrc = BT + (size_t)(col0 + brow) * KDIM + k0 + bhalf * 16;
        *(uint4*)(&Bs[brow][bhalf * 16])     = *(const uint4*)(bsrc);
        *(uint4*)(&Bs[brow][bhalf * 16 + 8]) = *(const uint4*)(bsrc + 8);
        __syncthreads();
        bf16x8 af[2], bfr[4];
        #pragma unroll
        for (int fm = 0; fm < 2; fm++)
            af[fm] = *(const bf16x8*)(&As[wm * 32 + fm * 16 + l15][lg * 8]);
        #pragma unroll
        for (int fn = 0; fn < 4; fn++)
            bfr[fn] = *(const bf16x8*)(&Bs[wn * 64 + fn * 16 + l15][lg * 8]);
        #pragma unroll
        for (int fm = 0; fm < 2; fm++)
            #pragma unroll
            for (int fn = 0; fn < 4; fn++)
                acc[fm][fn] = __builtin_amdgcn_mfma_f32_16x16x32_bf16(
                    af[fm], bfr[fn], acc[fm][fn], 0, 0, 0);
    }
    #pragma unroll
    for (int fm = 0; fm < 2; fm++)
        #pragma unroll
        for (int fn = 0; fn < 4; fn++) {
            int col = col0 + wn * 64 + fn * 16 + l15;
            float bvv = bias[col];
            #pragma unroll
            for (int r = 0; r < 4; r++) {
                int row = row0 + wm * 32 + fm * 16 + lg * 4 + r;
                float v = acc[fm][fn][r] + bvv;
                if (RELU) v = fmaxf(v, 0.f);
                v *= scale;
                if (OUTBF) ((unsigned short*)Cout)[(size_t)row * 256 + col] = f2bf(v);
                else       ((float*)Cout)[(size_t)row * 256 + col] = v;
            }
        }
}

__global__ __launch_bounds__(256, 2) void gemm512_kernel(
    const unsigned short* __restrict__ A,
    const unsigned short* __restrict__ BT,
    const float* __restrict__ bias,
    unsigned short* __restrict__ Cout)
{
    gemm_body<512, 1, 1>(A, BT, bias, (void*)Cout, 1.0f);
}

// ---------------- Vw body: Vw[row][h] = X[row]·Wvw[:,h] + bvw[h]
static __device__ __forceinline__ void vw_body(
    const unsigned short* __restrict__ Xbf,
    const float* __restrict__ Wvw,
    const float* __restrict__ bvw,
    float* __restrict__ Vw)
{
    __shared__ float sW[2048];
    __shared__ float sb[8];
    int t = threadIdx.x;
    #pragma unroll
    for (int i = 0; i < 8; i++) sW[i * 256 + t] = Wvw[i * 256 + t];
    if (t < 8) sb[t] = bvw[t];
    __syncthreads();
    int row = blockIdx.x * 256 + t;
    float acc[8];
    #pragma unroll
    for (int h = 0; h < 8; h++) acc[h] = sb[h];
    for (int d0 = 0; d0 < 32; d0++) {
        bf16x8 x = *(const bf16x8*)(Xbf + (size_t)row * 256 + d0 * 8);
        #pragma unroll
        for (int j = 0; j < 8; j++) {
            float xf = bf2f((unsigned short)x[j]);
            #pragma unroll
            for (int h = 0; h < 8; h++) acc[h] += xf * sW[(d0 * 8 + j) * 8 + h];
        }
    }
    *(float4*)(Vw + (size_t)row * 8)     = make_float4(acc[0], acc[1], acc[2], acc[3]);
    *(float4*)(Vw + (size_t)row * 8 + 4) = make_float4(acc[4], acc[5], acc[6], acc[7]);
}

// ---------------- fused Q-GEMM / K-GEMM / Vw in one launch (z selects)
__global__ __launch_bounds__(256, 2) void gemmQKV_kernel(
    const unsigned short* __restrict__ qbf,
    const unsigned short* __restrict__ WTq,
    const float* __restrict__ bq,
    unsigned short* __restrict__ Qbf,
    const unsigned short* __restrict__ Xbf,
    const unsigned short* __restrict__ WTk,
    const float* __restrict__ bk,
    unsigned short* __restrict__ Kbf,
    const float* __restrict__ Wvw,
    const float* __restrict__ bvw,
    float* __restrict__ Vw)
{
    if (blockIdx.z == 0) {
        gemm_body<256, 0, 1>(qbf, WTq, bq, (void*)Qbf, 0.17677669529663687f);
    } else if (blockIdx.z == 1) {
        gemm_body<256, 0, 1>(Xbf, WTk, bk, (void*)Kbf, 1.0f);
    } else {
        if (blockIdx.x >= 64 || blockIdx.y != 0) return;
        vw_body(Xbf, Wvw, bvw, Vw);
    }
}

// ---------------- attnD: denominator partials -> atomicAdd into den workspace
// grid 2048: id -> b (32) x qt (16) x kc (4); 256 threads = 4 waves
__global__ __launch_bounds__(256, 8) void attnD_kernel(
    const unsigned short* __restrict__ Qbf,
    const unsigned short* __restrict__ Kbf,
    const float* __restrict__ rel,
    const float* __restrict__ tsp,
    float* __restrict__ denp,    // [32][8][512]
    float* __restrict__ dent,    // [32][512]
    float* __restrict__ denr)    // [32][512]
{
    const int t = threadIdx.x;
    const int id = blockIdx.x;
    const int b  = id >> 6;
    const int qt = (id >> 2) & 15;
    const int kc = id & 3;
    const int q0 = qt * 32;
    const int w = t >> 6, lane = t & 63;
    const int l15 = lane & 15, lg = lane >> 4;

    // Q fragments for this wave's 2 heads
    bf16x8 aq[2][2];
    #pragma unroll
    for (int hh = 0; hh < 2; hh++)
        #pragma unroll
        for (int mf = 0; mf < 2; mf++)
            aq[hh][mf] = *(const bf16x8*)(Qbf +
                (size_t)(b * SEQ + q0 + mf * 16 + l15) * EMB + (2 * w + hh) * 32 + lg * 8);

    float dp[2][2][4] = {};
    #pragma unroll 1
    for (int i = 0; i < 4; i++) {
        const int kt = kc + 4 * i;
        if (kt > qt) break;
        const int k0 = kt * 32;
        #pragma unroll
        for (int hh = 0; hh < 2; hh++) {
            #pragma unroll
            for (int nf = 0; nf < 2; nf++) {
                bf16x8 bk = *(const bf16x8*)(Kbf +
                    (size_t)(b * SEQ + k0 + nf * 16 + l15) * EMB + (2 * w + hh) * 32 + lg * 8);
                const int kcol = k0 + nf * 16 + l15;
                #pragma unroll
                for (int mf = 0; mf < 2; mf++) {
                    f32x4 am = __builtin_amdgcn_mfma_f32_16x16x32_bf16(
                        aq[hh][mf], bk, (f32x4){0, 0, 0, 0}, 0, 0, 0);
                    #pragma unroll
                    for (int r = 0; r < 4; r++) {
                        const int qrow = q0 + mf * 16 + lg * 4 + r;
                        dp[hh][mf][r] += (kcol <= qrow) ? __expf(am[r]) : 0.f;
                    }
                }
            }
        }
    }

    // rel/ts: wave w handles tile kc + 4*w
    float dt[2][4] = {}, dr[2][4] = {};
    {
        const int kt2 = kc + 4 * w;
        if (kt2 <= qt) {
            const int k0 = kt2 * 32;
            #pragma unroll
            for (int mf = 0; mf < 2; mf++)
                #pragma unroll
                for (int r = 0; r < 4; r++) {
                    const int qrow = q0 + mf * 16 + lg * 4 + r;
                    const size_t base = ((size_t)(b * SEQ) + qrow) * SEQ + k0 + l15;
                    #pragma unroll
                    for (int nf = 0; nf < 2; nf++) {
                        const int kcol = k0 + nf * 16 + l15;
                        const bool va = kcol <= qrow;
                        float tv = tsp[base + nf * 16];
                        float rv = rel[base + nf * 16];
                        dt[mf][r] += va ? __expf(__expf(-fabsf(tv))) : 0.f;
                        dr[mf][r] += (va && rv != 0.f) ? __expf(rv) : 0.f;
                    }
                }
        }
    }

    // shfl-reduce over the 16 key lanes, then atomicAdd partials
    #pragma unroll
    for (int hh = 0; hh < 2; hh++)
        #pragma unroll
        for (int mf = 0; mf < 2; mf++)
            #pragma unroll
            for (int r = 0; r < 4; r++) {
                float v = dp[hh][mf][r];
                v += __shfl_xor(v, 1); v += __shfl_xor(v, 2);
                v += __shfl_xor(v, 4); v += __shfl_xor(v, 8);
                if (l15 == 0)
                    atomicAdd(&denp[((size_t)(b * NHEAD + 2 * w + hh)) * SEQ
                                    + q0 + mf * 16 + lg * 4 + r], v);
            }
    #pragma unroll
    for (int mf = 0; mf < 2; mf++)
        #pragma unroll
        for (int r = 0; r < 4; r++) {
            float v = dt[mf][r];
            v += __shfl_xor(v, 1); v += __shfl_xor(v, 2);
            v += __shfl_xor(v, 4); v += __shfl_xor(v, 8);
            float u = dr[mf][r];
            u += __shfl_xor(u, 1); u += __shfl_xor(u, 2);
            u += __shfl_xor(u, 4); u += __shfl_xor(u, 8);
            if (l15 == 0) {
                const int qrow = q0 + mf * 16 + lg * 4 + r;
                atomicAdd(&dent[b * SEQ + qrow], v);
                atomicAdd(&denr[b * SEQ + qrow], u);
            }
        }
}

// ---------------- attnW: uniform per-tile blocks; blend + LANE-coalesced writes
// grid 8192: id -> b (32) x tile (256 = qt*16+kt); 256 threads = 4 waves
__global__ __launch_bounds__(256, 4) void attnW_kernel(
    const unsigned short* __restrict__ Qbf,
    const unsigned short* __restrict__ Kbf,
    const float* __restrict__ Vw,
    const float* __restrict__ rel,
    const float* __restrict__ tsp,
    const float* __restrict__ denp,
    const float* __restrict__ dent,
    const float* __restrict__ denr,
    const float* __restrict__ pl1,
    const float* __restrict__ pl2,
    float* __restrict__ logits,
    float* __restrict__ attn)
{
    __shared__ float sT[NHEAD][32][33];
    __shared__ float slog[4][32];

    const int t = threadIdx.x;
    const int id = blockIdx.x;
    const int b = id >> 8;
    const int tile = id & 255;
    const int qt = tile >> 4, kt = tile & 15;
    const int q0 = qt * 32, k0 = kt * 32;

    // lane-coalesced write geometry: 8 lanes cover one full 128B row segment
    const int row_g = t >> 3;     // 0..31 concurrent row slot
    const int col4  = (t & 7) * 4;

    if (kt > qt) {   // strictly-future tile: zero-fill, 8 consecutive lanes per line
        const float4 z = make_float4(0.f, 0.f, 0.f, 0.f);
        #pragma unroll
        for (int step = 0; step < 8; step++) {
            const int ridx = step * 32 + row_g;       // 0..255
            const int h = ridx >> 5, qloc = ridx & 31;
            *(float4*)(attn + ((size_t)((b * NHEAD + h) * SEQ) + q0 + qloc) * SEQ
                       + k0 + col4) = z;
        }
        return;
    }

    const int w = t >> 6, lane = t & 63;
    const int l15 = lane & 15, lg = lane >> 4;
    const float l1 = pl1[0], l2 = pl2[0];
    const float cp = (1.f - l1) * (1.f - l2);
    const float ct = (1.f - l1) * l2;
    const float cr = l1;

    // per-row stats + et/er in C-frag layout
    float invt[2][4], invr[2][4], et[2][4][2], er[2][4][2];
    #pragma unroll
    for (int mf = 0; mf < 2; mf++)
        #pragma unroll
        for (int r = 0; r < 4; r++) {
            const int qrow = q0 + mf * 16 + lg * 4 + r;
            float dt = dent[b * SEQ + qrow];
            float dr = denr[b * SEQ + qrow];
            invt[mf][r] = 1.f / dt;
            invr[mf][r] = dr > 0.f ? 1.f / dr : 0.f;
            const size_t base = ((size_t)(b * SEQ) + qrow) * SEQ + k0 + l15;
            #pragma unroll
            for (int nf = 0; nf < 2; nf++) {
                const int kcol = k0 + nf * 16 + l15;
                const bool va = kcol <= qrow;
                float tv = tsp[base + nf * 16];
                float rv = rel[base + nf * 16];
                et[mf][r][nf] = va ? __expf(__expf(-fabsf(tv))) : 0.f;
                er[mf][r][nf] = (va && rv != 0.f) ? __expf(rv) : 0.f;
            }
        }

    float plog[2][4] = {};
    #pragma unroll 1
    for (int hh = 0; hh < 2; hh++) {
        const int h = 2 * w + hh;
        bf16x8 aq0 = *(const bf16x8*)(Qbf + (size_t)(b * SEQ + q0 + l15) * EMB + h * 32 + lg * 8);
        bf16x8 aq1 = *(const bf16x8*)(Qbf + (size_t)(b * SEQ + q0 + 16 + l15) * EMB + h * 32 + lg * 8);
        bf16x8 bk0 = *(const bf16x8*)(Kbf + (size_t)(b * SEQ + k0 + l15) * EMB + h * 32 + lg * 8);
        bf16x8 bk1 = *(const bf16x8*)(Kbf + (size_t)(b * SEQ + k0 + 16 + l15) * EMB + h * 32 + lg * 8);
        const float vw0 = Vw[(size_t)(b * SEQ + k0 + l15) * 8 + h];
        const float vw1 = Vw[(size_t)(b * SEQ + k0 + 16 + l15) * 8 + h];
        float invp[2][4];
        #pragma unroll
        for (int mf = 0; mf < 2; mf++)
            #pragma unroll
            for (int r = 0; r < 4; r++)
                invp[mf][r] = 1.f / denp[((size_t)(b * NHEAD + h)) * SEQ
                                         + q0 + mf * 16 + lg * 4 + r];
        f32x4 am[2][2];
        am[0][0] = __builtin_amdgcn_mfma_f32_16x16x32_bf16(aq0, bk0, (f32x4){0,0,0,0}, 0, 0, 0);
        am[0][1] = __builtin_amdgcn_mfma_f32_16x16x32_bf16(aq0, bk1, (f32x4){0,0,0,0}, 0, 0, 0);
        am[1][0] = __builtin_amdgcn_mfma_f32_16x16x32_bf16(aq1, bk0, (f32x4){0,0,0,0}, 0, 0, 0);
        am[1][1] = __builtin_amdgcn_mfma_f32_16x16x32_bf16(aq1, bk1, (f32x4){0,0,0,0}, 0, 0, 0);
        #pragma unroll
        for (int nf = 0; nf < 2; nf++) {
            const int kcol = k0 + nf * 16 + l15;
            const float vwv = nf ? vw1 : vw0;
            #pragma unroll
            for (int mf = 0; mf < 2; mf++)
                #pragma unroll
                for (int r = 0; r < 4; r++) {
                    const int qloc = mf * 16 + lg * 4 + r;
                    const int qrow = q0 + qloc;
                    float a = 0.f;
                    if (kcol <= qrow)
                        a = cp * __expf(am[mf][nf][r]) * invp[mf][r]
                          + ct * et[mf][r][nf] * invt[mf][r]
                          + cr * er[mf][r][nf] * invr[mf][r];
                    sT[h][qloc][nf * 16 + l15] = a;
                    plog[mf][r] = fmaf(a, vwv, plog[mf][r]);
                }
        }
    }
    __syncthreads();

    // lane-coalesced write-out: each step stores 8 full contiguous 128B lines
    #pragma unroll
    for (int step = 0; step < 8; step++) {
        const int ridx = step * 32 + row_g;           // 0..255
        const int h = ridx >> 5, qloc = ridx & 31;
        const float* s = &sT[h][qloc][col4];
        *(float4*)(attn + ((size_t)((b * NHEAD + h) * SEQ) + q0 + qloc) * SEQ
                   + k0 + col4) = make_float4(s[0], s[1], s[2], s[3]);
    }

    // logits partial: reduce over key lanes, cross-wave via LDS, one atomic per row
    #pragma unroll
    for (int mf = 0; mf < 2; mf++)
        #pragma unroll
        for (int r = 0; r < 4; r++) {
            float v = plog[mf][r];
            v += __shfl_xor(v, 1); v += __shfl_xor(v, 2);
            v += __shfl_xor(v, 4); v += __shfl_xor(v, 8);
            if (l15 == 0) slog[w][mf * 16 + lg * 4 + r] = v;
        }
    __syncthreads();
    if (t < 32)
        atomicAdd(&logits[b * SEQ + q0 + t],
                  slog[0][t] + slog[1][t] + slog[2][t] + slog[3][t]);
}

// ---------------- host launch ----------------
extern "C" void kernel_launch(void* const* d_in, const int* in_sizes, int n_in,
                              void* d_out, int out_size, void* d_ws, size_t ws_size,
                              hipStream_t stream)
{
    (void)in_sizes; (void)n_in; (void)out_size; (void)ws_size;
    const int*   item_inputs  = (const int*)d_in[0];
    const int*   label_inputs = (const int*)d_in[1];
    const int*   item_ids     = (const int*)d_in[2];
    const float* rel   = (const float*)d_in[3];
    const float* tsp   = (const float*)d_in[4];
    const float* emb   = (const float*)d_in[5];
    const float* W_in  = (const float*)d_in[6];
    const float* b_in  = (const float*)d_in[7];
    const float* Wq    = (const float*)d_in[8];
    const float* bq    = (const float*)d_in[9];
    const float* Wk    = (const float*)d_in[10];
    const float* bk    = (const float*)d_in[11];
    const float* Wv    = (const float*)d_in[12];
    const float* bv    = (const float*)d_in[13];
    const float* Wout  = (const float*)d_in[14];
    const float* bout  = (const float*)d_in[15];
    const float* l1    = (const float*)d_in[16];
    const float* l2    = (const float*)d_in[17];

    const size_t R = 16384;
    char* w = (char*)d_ws;
    unsigned short* Abig = (unsigned short*)w; w += R * 512 * 2;
    unsigned short* qbf  = (unsigned short*)w; w += R * 256 * 2;
    unsigned short* WTin = (unsigned short*)w; w += (size_t)256 * 512 * 2;
    unsigned short* WTq  = (unsigned short*)w; w += (size_t)256 * 256 * 2;
    unsigned short* WTk  = (unsigned short*)w; w += (size_t)256 * 256 * 2;
    unsigned short* Xbf  = (unsigned short*)w; w += R * 256 * 2;
    unsigned short* Qbf  = (unsigned short*)w; w += R * 256 * 2;
    unsigned short* Kbf  = (unsigned short*)w; w += R * 256 * 2;
    float* Wvw  = (float*)w; w += 2048 * 4;
    float* Vw   = (float*)w; w += R * 8 * 4;
    float* bvw  = (float*)w; w += 256;          // 8 floats + pad
    float* denp = (float*)w; w += (size_t)32 * NHEAD * SEQ * 4;   // 512 KB
    float* dent = (float*)w; w += (size_t)32 * SEQ * 4;           // 64 KB
    float* denr = (float*)w; w += (size_t)32 * SEQ * 4;           // 64 KB

    prep_kernel<<<dim3(4096), dim3(256), 0, stream>>>(
        item_inputs, label_inputs, item_ids, emb, Abig, qbf);
    // wcombo also zeroes denp/dent/denr (contiguous 163840 floats) and inits logits
    wcombo_kernel<<<dim3(1737), dim3(256), 0, stream>>>(
        W_in, Wq, Wk, Wv, Wout, bv, bout, WTin, WTq, WTk, Wvw, bvw,
        (float*)d_out, denp);

    gemm512_kernel<<<dim3(256, 2), dim3(256), 0, stream>>>(Abig, WTin, b_in, Xbf);
    gemmQKV_kernel<<<dim3(256, 2, 3), dim3(256), 0, stream>>>(
        qbf, WTq, bq, Qbf, Xbf, WTk, bk, Kbf, Wvw, bvw, Vw);

    float* logits = (float*)d_out;
    float* attnp  = (float*)d_out + 16384;
    attnD_kernel<<<dim3(2048), dim3(256), 0, stream>>>(
        Qbf, Kbf, rel, tsp, denp, dent, denr);
    attnW_kernel<<<dim3(8192), dim3(256), 0, stream>>>(
        Qbf, Kbf, Vw, rel, tsp, denp, dent, denr, l1, l2, logits, attnp);
}